// Round 1
// 194.240 us; speedup vs baseline: 1.4492x; 1.4492x over previous
//
#include <hip/hip_runtime.h>

#define NB 32
#define W 512
#define H 512
#define BLOCK 512
#define BAND 32
#define RS 4
#define NSTEP (BAND / RS)
#define PADW 524          // 512 + 5+7 halo; multiple of 4 -> 16B-aligned rows for b128
#define C2f 0.0009f

// normalized gaussian(11, sigma=1.5)
#define GW0 0.001028381f
#define GW1 0.007598758f
#define GW2 0.036000773f
#define GW3 0.109360700f
#define GW4 0.213005540f
#define GW5 0.266011720f

__device__ __forceinline__ float gwv(int k) {
    const float g[11] = {GW0, GW1, GW2, GW3, GW4, GW5, GW4, GW3, GW2, GW1, GW0};
    return g[k];
}

// column load, y-guard only (x == col is always in range for the conv path)
template<bool GY>
__device__ __forceinline__ float ldy(const float* __restrict__ p, int gy, int col) {
    if (GY) {
        bool ok = (unsigned)gy < H;
        int cy = min(max(gy, 0), H - 1);
        float v = p[cy * W + col];
        return ok ? v : 0.f;
    }
    return p[gy * W + col];
}

// sobel load: x-guard always (zero pad), y-guard only on edge bands
template<bool GY>
__device__ __forceinline__ float ldxy(const float* __restrict__ p, int gy, int gx) {
    int cx = min(max(gx, 0), W - 1);
    if (GY) {
        bool ok = ((unsigned)gx < W) && ((unsigned)gy < H);
        int cy = min(max(gy, 0), H - 1);
        float v = p[cy * W + cx];
        return ok ? v : 0.f;
    }
    float v = p[gy * W + cx];
    return ((unsigned)gx < W) ? v : 0.f;
}

__device__ __forceinline__ float sob3(const float r0[3], const float r1[3],
                                      const float r2[3]) {
    float gx = (r0[2] - r0[0]) + 2.f * (r1[2] - r1[0]) + (r2[2] - r2[0]);
    float gy = (r0[0] - r2[0]) + 2.f * (r0[1] - r2[1]) + (r0[2] - r2[2]);
    return fabsf(gx) + fabsf(gy);
}

// vertical 11-tap for ALL 8 quantities in one streaming pass over 14 rows.
// thread owns one column; 42 independent coalesced loads per step.
template<bool GY>
__device__ __forceinline__ void vstep(
    const float* __restrict__ pg, const float* __restrict__ pi,
    const float* __restrict__ pv, float* __restrict__ vsf,
    int rbase, int col) {
    float acc[RS][8];
    #pragma unroll
    for (int j = 0; j < RS; ++j)
        #pragma unroll
        for (int q = 0; q < 8; ++q) acc[j][q] = 0.f;

    #pragma unroll
    for (int k = 0; k < RS + 10; ++k) {
        int gy = rbase - 5 + k;
        float a = ldy<GY>(pg, gy, col);   // gen
        float b = ldy<GY>(pi, gy, col);   // ir
        float c = ldy<GY>(pv, gy, col);   // vis
        float aa = a * a, bb = b * b, cc = c * c, ab = a * b, ac = a * c;
        #pragma unroll
        for (int j = 0; j < RS; ++j) {
            int t = k - j;
            if (t >= 0 && t <= 10) {
                float w = gwv(t);
                acc[j][0] = fmaf(w, a,  acc[j][0]);
                acc[j][1] = fmaf(w, b,  acc[j][1]);
                acc[j][2] = fmaf(w, c,  acc[j][2]);
                acc[j][3] = fmaf(w, aa, acc[j][3]);
                acc[j][4] = fmaf(w, bb, acc[j][4]);
                acc[j][5] = fmaf(w, cc, acc[j][5]);
                acc[j][6] = fmaf(w, ab, acc[j][6]);
                acc[j][7] = fmaf(w, ac, acc[j][7]);
            }
        }
    }
    #pragma unroll
    for (int j = 0; j < RS; ++j)
        #pragma unroll
        for (int q = 0; q < 8; ++q)
            vsf[(q * RS + j) * PADW + 5 + col] = acc[j][q];
}

// sobel + intensity for this column, 4 output rows, sliding 3x3.
template<bool GY>
__device__ __forceinline__ void sobstep(
    const float* __restrict__ pg, const float* __restrict__ pi,
    const float* __restrict__ pv, int rbase, int col,
    float& s_in, float& s_grad) {
    float g0[3], g1[3], g2[3], i0[3], i1[3], i2[3], v0[3], v1[3], v2[3];
    #pragma unroll
    for (int c = 0; c < 3; ++c) {
        int gx = col - 1 + c;
        g0[c] = ldxy<GY>(pg, rbase - 1, gx);
        i0[c] = ldxy<GY>(pi, rbase - 1, gx);
        v0[c] = ldxy<GY>(pv, rbase - 1, gx);
        g1[c] = ldxy<GY>(pg, rbase, gx);
        i1[c] = ldxy<GY>(pi, rbase, gx);
        v1[c] = ldxy<GY>(pv, rbase, gx);
    }
    #pragma unroll
    for (int j = 0; j < RS; ++j) {
        int gy = rbase + 1 + j;
        #pragma unroll
        for (int c = 0; c < 3; ++c) {
            int gx = col - 1 + c;
            g2[c] = ldxy<GY>(pg, gy, gx);
            i2[c] = ldxy<GY>(pi, gy, gx);
            v2[c] = ldxy<GY>(pv, gy, gx);
        }
        s_in += fabsf(g1[1] - fmaxf(v1[1], i1[1]));
        float sg = sob3(g0, g1, g2);
        float si = sob3(i0, i1, i2);
        float sv = sob3(v0, v1, v2);
        s_grad += fabsf(sg - fmaxf(sv, si));
        #pragma unroll
        for (int c = 0; c < 3; ++c) {
            g0[c] = g1[c]; g1[c] = g2[c];
            i0[c] = i1[c]; i1[c] = i2[c];
            v0[c] = v1[c]; v1[c] = v2[c];
        }
    }
}

// horizontal 11-tap via float4 (ds_read_b128); thread owns (row r, 4-col chunk)
__device__ __forceinline__ void hstep(const float* __restrict__ vsf, int tid,
                                      float& s_ssim) {
    int r = tid & 3;
    int xb = (tid >> 2) << 2;
    float res[8][4];
    #pragma unroll
    for (int q = 0; q < 8; ++q) {
        const float4* rp =
            reinterpret_cast<const float4*>(vsf + (q * RS + r) * PADW + xb);
        float4 A = rp[0], B = rp[1], C = rp[2], D = rp[3];
        float w[16] = {A.x, A.y, A.z, A.w, B.x, B.y, B.z, B.w,
                       C.x, C.y, C.z, C.w, D.x, D.y, D.z, D.w};
        #pragma unroll
        for (int j = 0; j < 4; ++j) {
            float acc = 0.f;
            #pragma unroll
            for (int t = 0; t < 11; ++t) acc = fmaf(gwv(t), w[j + t], acc);
            res[q][j] = acc;
        }
    }
    #pragma unroll
    for (int j = 0; j < 4; ++j) {
        float m1 = res[0][j], m2 = res[1][j], m3 = res[2][j];
        float sig1 = res[3][j] - m1 * m1;
        float sig2 = res[4][j] - m2 * m2;
        float sig3 = res[5][j] - m3 * m3;
        float sg12 = res[6][j] - m1 * m2;
        float sg13 = res[7][j] - m1 * m3;
        float x2 = sqrtf(sig2);
        float x3 = sqrtf(sig3);
        float map12 = (2.f * sg12 + C2f) / (sig1 + sig2 + C2f);
        float map13 = (2.f * sg13 + C2f) / (sig1 + sig3 + C2f);
        // matches jnp.where(|x2| >= |x3|, map12, map13); NaN -> map13
        s_ssim += (fabsf(x2) >= fabsf(x3)) ? map12 : map13;
    }
}

__global__ __launch_bounds__(BLOCK, 4) void fusion_main(
    const float* __restrict__ vis, const float* __restrict__ ir,
    const float* __restrict__ gen, double* __restrict__ sums) {
    __shared__ float vsf[8 * RS * PADW];   // 67072 B
    __shared__ float red[3][8];
    const size_t off = (size_t)blockIdx.z * (H * W);
    const int y0 = blockIdx.y * BAND;
    const int tid = threadIdx.x;
    const float* pv = vis + off;
    const float* pi = ir + off;
    const float* pg = gen + off;

    // zero the horizontal halo once (cols 0..4 and 517..523 of every plane-row)
    if (tid < 8 * RS * 12) {
        int plane = tid / 12;
        int rem = tid - plane * 12;
        int idx = (rem < 5) ? rem : (512 + rem);
        vsf[plane * PADW + idx] = 0.f;
    }
    __syncthreads();

    float s_in = 0.f, s_grad = 0.f, s_ssim = 0.f;
    bool interior = (blockIdx.y >= 1) && (blockIdx.y <= (H / BAND) - 2);

    if (interior) {
        for (int s = 0; s < NSTEP; ++s) {
            int rbase = y0 + s * RS;
            vstep<false>(pg, pi, pv, vsf, rbase, tid);
            __syncthreads();
            sobstep<false>(pg, pi, pv, rbase, tid, s_in, s_grad);
            hstep(vsf, tid, s_ssim);
            __syncthreads();
        }
    } else {
        for (int s = 0; s < NSTEP; ++s) {
            int rbase = y0 + s * RS;
            vstep<true>(pg, pi, pv, vsf, rbase, tid);
            __syncthreads();
            sobstep<true>(pg, pi, pv, rbase, tid, s_in, s_grad);
            hstep(vsf, tid, s_ssim);
            __syncthreads();
        }
    }

    #pragma unroll
    for (int o = 32; o > 0; o >>= 1) {
        s_in   += __shfl_down(s_in, o);
        s_grad += __shfl_down(s_grad, o);
        s_ssim += __shfl_down(s_ssim, o);
    }
    int lane = tid & 63, wv = tid >> 6;
    if (lane == 0) { red[0][wv] = s_in; red[1][wv] = s_grad; red[2][wv] = s_ssim; }
    __syncthreads();
    if (tid == 0) {
        float a = 0.f, b = 0.f, c = 0.f;
        #pragma unroll
        for (int k = 0; k < 8; ++k) { a += red[0][k]; b += red[1][k]; c += red[2][k]; }
        atomicAdd(&sums[0], (double)a);
        atomicAdd(&sums[1], (double)b);
        atomicAdd(&sums[2], (double)c);
    }
}

__global__ void finalize(const double* __restrict__ sums, float* __restrict__ out) {
    const double inv = 1.0 / ((double)NB * H * W);
    out[0] = (float)(1.5 * sums[0] * inv);
    out[1] = (float)(0.5 * (1.0 - sums[2] * inv) + sums[1] * inv);
}

extern "C" void kernel_launch(void* const* d_in, const int* in_sizes, int n_in,
                              void* d_out, int out_size, void* d_ws, size_t ws_size,
                              hipStream_t stream) {
    const float* vis = (const float*)d_in[0];
    const float* ir  = (const float*)d_in[1];
    const float* gen = (const float*)d_in[2];
    float* out = (float*)d_out;
    double* sums = (double*)d_ws;

    hipMemsetAsync(d_ws, 0, 3 * sizeof(double), stream);
    dim3 grid(1, H / BAND, NB);
    fusion_main<<<grid, BLOCK, 0, stream>>>(vis, ir, gen, sums);
    finalize<<<1, 1, 0, stream>>>(sums, out);
}